// Round 1
// baseline (29.719 us; speedup 1.0000x reference)
//
#include <hip/hip_runtime.h>
#include <hip/hip_bf16.h>

typedef __bf16 bf16x8 __attribute__((ext_vector_type(8)));
typedef float f32x4 __attribute__((ext_vector_type(4)));

#define BATCH 2048
#define NEGS 512
#define IN_DIM 256
#define DIM 64
#define NGATE 384          // 6 * 64
#define EMB_LD 72          // padded bf16 row stride (16B-aligned, odd multiple of 8 dwords -> balanced banks)
#define TAB_LD 33          // padded table row stride: bank = (u+v)%32

__device__ inline bf16x8 cvt8(float4 f0, float4 f1) {
    bf16x8 r;
    r[0] = (__bf16)f0.x; r[1] = (__bf16)f0.y; r[2] = (__bf16)f0.z; r[3] = (__bf16)f0.w;
    r[4] = (__bf16)f1.x; r[5] = (__bf16)f1.y; r[6] = (__bf16)f1.z; r[7] = (__bf16)f1.w;
    return r;
}

// ---------------- Kernel 1: gates g[b][p*64+d] = tanh(x[b,:] . gate_w[p,d,:] + gate_b[p,d]) ----
// GEMM M=2048, N=384, K=256. 32x32 tile per 1-wave block via mfma_f32_16x16x32_bf16.
// Fragment k-mapping: position (q=l>>4, i) -> k = 32*s + 8*q + i (contiguous 8; any consistent
// K-bijection used for BOTH A and B cancels in the contraction).
__global__ __launch_bounds__(64) void gate_gemm_kernel(
    const float* __restrict__ x, const float* __restrict__ gw,
    const float* __restrict__ gb, float* __restrict__ g)
{
    const int l = threadIdx.x;
    const int lm = l & 15, lq = l >> 4;
    const int m0 = blockIdx.x * 32;   // batch tile
    const int n0 = blockIdx.y * 32;   // gate-row tile
    f32x4 acc[2][2] = {};

#pragma unroll
    for (int s = 0; s < 8; ++s) {
        const int k0 = s * 32 + lq * 8;
        bf16x8 af[2], bfr[2];
#pragma unroll
        for (int mh = 0; mh < 2; ++mh) {
            const float* p = x + (size_t)(m0 + mh * 16 + lm) * IN_DIM + k0;
            af[mh] = cvt8(*(const float4*)p, *(const float4*)(p + 4));
        }
#pragma unroll
        for (int nh = 0; nh < 2; ++nh) {
            const float* p = gw + (size_t)(n0 + nh * 16 + lm) * IN_DIM + k0;
            bfr[nh] = cvt8(*(const float4*)p, *(const float4*)(p + 4));
        }
#pragma unroll
        for (int mh = 0; mh < 2; ++mh)
#pragma unroll
            for (int nh = 0; nh < 2; ++nh)
                acc[mh][nh] = __builtin_amdgcn_mfma_f32_16x16x32_bf16(af[mh], bfr[nh], acc[mh][nh], 0, 0, 0);
    }

    // Epilogue: C/D layout (verified): col = lane&15, row = (lane>>4)*4 + reg
#pragma unroll
    for (int mh = 0; mh < 2; ++mh) {
#pragma unroll
        for (int nh = 0; nh < 2; ++nh) {
            const int gc = n0 + nh * 16 + lm;
            const float bias = gb[gc];
#pragma unroll
            for (int r = 0; r < 4; ++r) {
                const int gr = m0 + mh * 16 + lq * 4 + r;
                g[(size_t)gr * NGATE + gc] = tanhf(acc[mh][nh][r] + bias);
            }
        }
    }
}

// ---------------- Kernel 2: per-b pair tables via MFMA, then table-lookup scoring -------------
// emb rows (sorted heads): cf_perm=0, cf_primary=1, cf_secondary=2, predictor=3, reorder=4
// label cols: predictor=0, cf_perm=1, cf_primary=2, cf_secondary=3, reorder=4 (5=interleave unused)
// pairs p: a-head = pred(p<3) / reorder(p>=3), c-head = p%3 (perm/primary/secondary)
__global__ __launch_bounds__(256) void table_score_kernel(
    const int* __restrict__ labels, const float* __restrict__ emb,
    const float* __restrict__ g, float* __restrict__ out)
{
    __shared__ __align__(16) __bf16 embs[5 * 32 * EMB_LD];   // 23040 B
    __shared__ __align__(16) float tab[2 * 6 * 32 * TAB_LD]; // 50688 B

    const int t = threadIdx.x;
    const int b0 = blockIdx.x * 2;

    // ---- stage emb: f32 global -> bf16 LDS (padded) ----
#pragma unroll
    for (int c = 0; c < 5; ++c) {
        const int j = t + c * 256;            // 1280 chunks of 8 elems
        const int head = j >> 8;
        const int rem = j & 255;
        const int v = rem >> 3, q = rem & 7;
        const float4* src = (const float4*)(emb + (size_t)j * 8);
        bf16x8 val = cvt8(src[0], src[1]);
        *(bf16x8*)&embs[head * (32 * EMB_LD) + v * EMB_LD + q * 8] = val;
    }
    __syncthreads();

    // ---- build 12 tables (2 b's x 6 pairs), 3 per wave ----
    const int w = t >> 6, l = t & 63;
    const int lm = l & 15, lq = l >> 4;

    for (int id = w; id < 12; id += 4) {
        const int bi = id / 6, p = id % 6;
        const int b = b0 + bi;
        const int arow = (p < 3) ? 3 : 4;        // predictor / reorder
        const int crow = (p < 3) ? p : p - 3;    // cf_perm / cf_primary / cf_secondary
        f32x4 acc[2][2] = {};

#pragma unroll
        for (int s = 0; s < 2; ++s) {
            const int k0 = s * 32 + lq * 8;      // d-offset for this lane's positions
            // gate values for this lane's 8 d's (f32, L2-hit, broadcast within 16-lane groups)
            const float* gp = g + (size_t)b * NGATE + p * 64 + k0;
            const float4 g0 = *(const float4*)gp;
            const float4 g1 = *(const float4*)(gp + 4);

            bf16x8 bfr[2], afr[2];
#pragma unroll
            for (int nh = 0; nh < 2; ++nh)
                bfr[nh] = *(const bf16x8*)&embs[crow * (32 * EMB_LD) + (nh * 16 + lm) * EMB_LD + k0];
#pragma unroll
            for (int mh = 0; mh < 2; ++mh) {
                bf16x8 ea = *(const bf16x8*)&embs[arow * (32 * EMB_LD) + (mh * 16 + lm) * EMB_LD + k0];
                bf16x8 r;
                r[0] = (__bf16)((float)ea[0] * g0.x); r[1] = (__bf16)((float)ea[1] * g0.y);
                r[2] = (__bf16)((float)ea[2] * g0.z); r[3] = (__bf16)((float)ea[3] * g0.w);
                r[4] = (__bf16)((float)ea[4] * g1.x); r[5] = (__bf16)((float)ea[5] * g1.y);
                r[6] = (__bf16)((float)ea[6] * g1.z); r[7] = (__bf16)((float)ea[7] * g1.w);
                afr[mh] = r;
            }
#pragma unroll
            for (int mh = 0; mh < 2; ++mh)
#pragma unroll
                for (int nh = 0; nh < 2; ++nh)
                    acc[mh][nh] = __builtin_amdgcn_mfma_f32_16x16x32_bf16(afr[mh], bfr[nh], acc[mh][nh], 0, 0, 0);
        }

        // write table: T[u][v], u from A-side (row), v from B-side (col)
        float* tb = tab + id * (32 * TAB_LD);
#pragma unroll
        for (int mh = 0; mh < 2; ++mh)
#pragma unroll
            for (int nh = 0; nh < 2; ++nh) {
                const int col = nh * 16 + lm;
#pragma unroll
                for (int r = 0; r < 4; ++r)
                    tb[(mh * 16 + lq * 4 + r) * TAB_LD + col] = acc[mh][nh][r];
            }
    }
    __syncthreads();

    // ---- score: thread t handles negs {2t, 2t+1} for each of the 2 b's ----
#pragma unroll
    for (int bi = 0; bi < 2; ++bi) {
        const int b = b0 + bi;
        const int4* lp = (const int4*)(labels + (size_t)b * NEGS * 6) + 3 * t;
        const int4 q0 = lp[0];   // negA: cols 0..3
        const int4 q1 = lp[1];   // negA: col4, col5 | negB: col0, col1
        const int4 q2 = lp[2];   // negB: cols 2..5
        const float* tb = tab + bi * (6 * 32 * TAB_LD);

        const float sA =
            tb[0 * 32 * TAB_LD + q0.x * TAB_LD + q0.y] +
            tb[1 * 32 * TAB_LD + q0.x * TAB_LD + q0.z] +
            tb[2 * 32 * TAB_LD + q0.x * TAB_LD + q0.w] +
            tb[3 * 32 * TAB_LD + q1.x * TAB_LD + q0.y] +
            tb[4 * 32 * TAB_LD + q1.x * TAB_LD + q0.z] +
            tb[5 * 32 * TAB_LD + q1.x * TAB_LD + q0.w];
        const float sB =
            tb[0 * 32 * TAB_LD + q1.z * TAB_LD + q1.w] +
            tb[1 * 32 * TAB_LD + q1.z * TAB_LD + q2.x] +
            tb[2 * 32 * TAB_LD + q1.z * TAB_LD + q2.y] +
            tb[3 * 32 * TAB_LD + q2.z * TAB_LD + q1.w] +
            tb[4 * 32 * TAB_LD + q2.z * TAB_LD + q2.x] +
            tb[5 * 32 * TAB_LD + q2.z * TAB_LD + q2.y];

        float2 res; res.x = sA; res.y = sB;
        *(float2*)(out + (size_t)b * NEGS + 2 * t) = res;
    }
}

extern "C" void kernel_launch(void* const* d_in, const int* in_sizes, int n_in,
                              void* d_out, int out_size, void* d_ws, size_t ws_size,
                              hipStream_t stream) {
    const float* x      = (const float*)d_in[0];
    const int*   labels = (const int*)d_in[1];
    const float* emb    = (const float*)d_in[2];
    const float* gw     = (const float*)d_in[3];
    const float* gb     = (const float*)d_in[4];
    float* out = (float*)d_out;
    float* g   = (float*)d_ws;   // 2048*384 f32 = 3 MB

    hipLaunchKernelGGL(gate_gemm_kernel, dim3(BATCH / 32, NGATE / 32), dim3(64), 0, stream,
                       x, gw, gb, g);
    hipLaunchKernelGGL(table_score_kernel, dim3(BATCH / 2), dim3(256), 0, stream,
                       labels, emb, g, out);
}

// Round 2
// 27.115 us; speedup vs baseline: 1.0960x; 1.0960x over previous
//
#include <hip/hip_runtime.h>
#include <hip/hip_bf16.h>

typedef __bf16 bf16x8 __attribute__((ext_vector_type(8)));
typedef float f32x4 __attribute__((ext_vector_type(4)));

#define BATCH 2048
#define NEGS 512
#define IN_DIM 256
#define NGATE 384          // 6 * 64
#define EMB_LD 72          // padded bf16 row stride (144B rows: b128 reads spread over all 8 16B slots)
#define TAB_LD 34          // bf16 table row stride (68B, dword-aligned)

__device__ inline bf16x8 cvt8(float4 f0, float4 f1) {
    bf16x8 r;
    r[0] = (__bf16)f0.x; r[1] = (__bf16)f0.y; r[2] = (__bf16)f0.z; r[3] = (__bf16)f0.w;
    r[4] = (__bf16)f1.x; r[5] = (__bf16)f1.y; r[6] = (__bf16)f1.z; r[7] = (__bf16)f1.w;
    return r;
}

// ---------------- Kernel 1: g[b][p*64+d] = tanh(x[b,:] . gate_w[p,d,:] + gate_b[p,d]) -> bf16
// GEMM M=2048, N=384, K=256. One 16x16 tile per wave (3072 tiles, 768 blocks x 4 waves
// = 12 waves/CU for latency hiding; 2 loads + 1 MFMA per k-step keeps VGPR low).
__global__ __launch_bounds__(256) void gate_gemm_kernel(
    const float* __restrict__ x, const float* __restrict__ gw,
    const float* __restrict__ gb, __bf16* __restrict__ g)
{
    const int w = threadIdx.x >> 6, l = threadIdx.x & 63;
    const int lm = l & 15, lq = l >> 4;
    const int tile = blockIdx.x * 4 + w;      // 0..3071
    const int mt = tile / 24, nt = tile % 24; // consecutive tiles share x rows (L2)
    const int m0 = mt * 16, n0 = nt * 16;

    const float* xp = x + (size_t)(m0 + lm) * IN_DIM + lq * 8;
    const float* wp = gw + (size_t)(n0 + lm) * IN_DIM + lq * 8;
    f32x4 acc = {};
#pragma unroll
    for (int s = 0; s < 8; ++s) {
        bf16x8 a = cvt8(*(const float4*)(xp + s * 32), *(const float4*)(xp + s * 32 + 4));
        bf16x8 b = cvt8(*(const float4*)(wp + s * 32), *(const float4*)(wp + s * 32 + 4));
        acc = __builtin_amdgcn_mfma_f32_16x16x32_bf16(a, b, acc, 0, 0, 0);
    }
    // C/D layout: col = lane&15, row = (lane>>4)*4 + reg
    const int col = n0 + lm;
    const float bias = gb[col];
#pragma unroll
    for (int r = 0; r < 4; ++r) {
        const int row = m0 + lq * 4 + r;
        g[(size_t)row * NGATE + col] = (__bf16)tanhf(acc[r] + bias);
    }
}

// ---------------- Kernel 2: per-b pair tables via MFMA, then table-lookup scoring -------------
// emb rows (sorted heads): cf_perm=0, cf_primary=1, cf_secondary=2, predictor=3, reorder=4
// label cols: predictor=0, cf_perm=1, cf_primary=2, cf_secondary=3, reorder=4 (5 unused)
// pairs p: a-head = pred(p<3)/reorder(p>=3), c-head = p%3
__global__ __launch_bounds__(256, 3) void table_score_kernel(
    const int* __restrict__ labels, const float* __restrict__ emb,
    const __bf16* __restrict__ g, float* __restrict__ out)
{
    __shared__ __align__(16) __bf16 embs[5 * 32 * EMB_LD];    // 23040 B
    __shared__ __align__(16) __bf16 tab[2 * 6 * 32 * TAB_LD]; // 26112 B  (total 48 KB -> 3 blk/CU)

    const int t = threadIdx.x;
    const int b0 = blockIdx.x * 2;
    const int w = t >> 6, l = t & 63;
    const int lm = l & 15, lq = l >> 4;

    // ---- prefetch labels (HBM, ~900cy) and gate fragments early: latency hides under staging+build
    int4 q[2][3];
#pragma unroll
    for (int bi = 0; bi < 2; ++bi) {
        const int4* lp = (const int4*)(labels + (size_t)(b0 + bi) * NEGS * 6) + 3 * t;
        q[bi][0] = lp[0]; q[bi][1] = lp[1]; q[bi][2] = lp[2];
    }
    bf16x8 gv[3][2];
#pragma unroll
    for (int j = 0; j < 3; ++j) {
        const int id = w + j * 4;            // table id this wave builds
        const int bi = id / 6, p = id % 6;
        const __bf16* gp = g + (size_t)(b0 + bi) * NGATE + p * 64 + lq * 8;
        gv[j][0] = *(const bf16x8*)gp;
        gv[j][1] = *(const bf16x8*)(gp + 32);
    }

    // ---- stage emb: f32 global -> bf16 LDS (padded) ----
#pragma unroll
    for (int c = 0; c < 5; ++c) {
        const int j = t + c * 256;           // 1280 chunks of 8 elems
        const int head = j >> 8;
        const int rem = j & 255;
        const int v = rem >> 3, qq = rem & 7;
        const float4* src = (const float4*)(emb + (size_t)j * 8);
        bf16x8 val = cvt8(src[0], src[1]);
        *(bf16x8*)&embs[head * (32 * EMB_LD) + v * EMB_LD + qq * 8] = val;
    }
    __syncthreads();

    // ---- build 12 tables (2 b's x 6 pairs), 3 per wave ----
#pragma unroll
    for (int j = 0; j < 3; ++j) {
        const int id = w + j * 4;
        const int p = id % 6;
        const int arow = (p < 3) ? 3 : 4;     // predictor / reorder
        const int crow = (p < 3) ? p : p - 3; // cf_perm / cf_primary / cf_secondary
        f32x4 acc[2][2] = {};

#pragma unroll
        for (int s = 0; s < 2; ++s) {
            const int k0 = s * 32 + lq * 8;
            float gf[8];
#pragma unroll
            for (int i = 0; i < 8; ++i) gf[i] = (float)gv[j][s][i];

            bf16x8 bfr[2], afr[2];
#pragma unroll
            for (int nh = 0; nh < 2; ++nh)
                bfr[nh] = *(const bf16x8*)&embs[crow * (32 * EMB_LD) + (nh * 16 + lm) * EMB_LD + k0];
#pragma unroll
            for (int mh = 0; mh < 2; ++mh) {
                bf16x8 ea = *(const bf16x8*)&embs[arow * (32 * EMB_LD) + (mh * 16 + lm) * EMB_LD + k0];
                bf16x8 r;
#pragma unroll
                for (int i = 0; i < 8; ++i) r[i] = (__bf16)((float)ea[i] * gf[i]);
                afr[mh] = r;
            }
#pragma unroll
            for (int mh = 0; mh < 2; ++mh)
#pragma unroll
                for (int nh = 0; nh < 2; ++nh)
                    acc[mh][nh] = __builtin_amdgcn_mfma_f32_16x16x32_bf16(afr[mh], bfr[nh], acc[mh][nh], 0, 0, 0);
        }

        __bf16* tb = tab + id * (32 * TAB_LD);
#pragma unroll
        for (int mh = 0; mh < 2; ++mh)
#pragma unroll
            for (int nh = 0; nh < 2; ++nh) {
                const int col = nh * 16 + lm;
#pragma unroll
                for (int r = 0; r < 4; ++r)
                    tb[(mh * 16 + lq * 4 + r) * TAB_LD + col] = (__bf16)acc[mh][nh][r];
            }
    }
    __syncthreads();

    // ---- score: thread t handles negs {2t, 2t+1} for each of the 2 b's (labels already in regs)
#pragma unroll
    for (int bi = 0; bi < 2; ++bi) {
        const int b = b0 + bi;
        const int4 q0 = q[bi][0];  // negA: cols 0..3
        const int4 q1 = q[bi][1];  // negA: col4, col5 | negB: col0, col1
        const int4 q2 = q[bi][2];  // negB: cols 2..5
        const __bf16* tb = tab + bi * (6 * 32 * TAB_LD);

        const float sA =
            (float)tb[0 * 32 * TAB_LD + q0.x * TAB_LD + q0.y] +
            (float)tb[1 * 32 * TAB_LD + q0.x * TAB_LD + q0.z] +
            (float)tb[2 * 32 * TAB_LD + q0.x * TAB_LD + q0.w] +
            (float)tb[3 * 32 * TAB_LD + q1.x * TAB_LD + q0.y] +
            (float)tb[4 * 32 * TAB_LD + q1.x * TAB_LD + q0.z] +
            (float)tb[5 * 32 * TAB_LD + q1.x * TAB_LD + q0.w];
        const float sB =
            (float)tb[0 * 32 * TAB_LD + q1.z * TAB_LD + q1.w] +
            (float)tb[1 * 32 * TAB_LD + q1.z * TAB_LD + q2.x] +
            (float)tb[2 * 32 * TAB_LD + q1.z * TAB_LD + q2.y] +
            (float)tb[3 * 32 * TAB_LD + q2.z * TAB_LD + q1.w] +
            (float)tb[4 * 32 * TAB_LD + q2.z * TAB_LD + q2.x] +
            (float)tb[5 * 32 * TAB_LD + q2.z * TAB_LD + q2.y];

        float2 res; res.x = sA; res.y = sB;
        *(float2*)(out + (size_t)b * NEGS + 2 * t) = res;
    }
}

extern "C" void kernel_launch(void* const* d_in, const int* in_sizes, int n_in,
                              void* d_out, int out_size, void* d_ws, size_t ws_size,
                              hipStream_t stream) {
    const float* x      = (const float*)d_in[0];
    const int*   labels = (const int*)d_in[1];
    const float* emb    = (const float*)d_in[2];
    const float* gw     = (const float*)d_in[3];
    const float* gb     = (const float*)d_in[4];
    float* out = (float*)d_out;
    __bf16* g  = (__bf16*)d_ws;   // 2048*384 bf16 = 1.5 MB

    hipLaunchKernelGGL(gate_gemm_kernel, dim3(768), dim3(256), 0, stream, x, gw, gb, g);
    hipLaunchKernelGGL(table_score_kernel, dim3(BATCH / 2), dim3(256), 0, stream,
                       labels, emb, g, out);
}